// Round 13
// baseline (146.749 us; speedup 1.0000x reference)
//
#include <hip/hip_runtime.h>
#include <hip/hip_bf16.h>

#define DIM 768
#define NE 64
#define NFRQ 2048
#define NB 32
#define HALF 384                // computed quadrant extent (y,x in [0,384))
#define KROW 1536               // BT per-x row elems: [ReP|-ImP|ReM|-ImM] x 384
#define KG 768                  // GEMM K per parity (384 cos + 384 sin)
#define TWO_PI 6.283185307179586f
#define INV768 (1.0f / 768.0f)
#define SCALE (300.0f / (float)(DIM * DIM))   // ALPHA / (dim*dim), folded into values

typedef __attribute__((ext_vector_type(8))) short bf16x8;   // 8 bf16 (4 VGPRs)
typedef __attribute__((ext_vector_type(4))) float f32x4;    // MFMA accumulator

// ---------------------------------------------------------------------------
// Kernel A "prep" (one launch, 3 roles by blockIdx)  [unchanged from R12]
// ---------------------------------------------------------------------------
__global__ __launch_bounds__(256) void prep_kernel(const float* __restrict__ cls,
                                                   const float* __restrict__ W,
                                                   const float* __restrict__ bias,
                                                   const float* __restrict__ coeff,
                                                   const int* __restrict__ lidx,
                                                   int* __restrict__ row_start,
                                                   float2* __restrict__ s_cv,
                                                   __hip_bfloat16* __restrict__ A,
                                                   float2* __restrict__ T2) {
  int bid = blockIdx.x;
  int tid = threadIdx.x;

  if (bid >= 32 + 2 * 192) {          // ---- T2 rows ----
    int c = bid - (32 + 2 * 192);     // 0..767
    for (int x = tid; x < HALF; x += 256) {
      float prod = (float)(c * x);    // < 2^24, exact
      float f, sn, cs;
      float rev = prod * INV768;
      asm("v_fract_f32 %0, %1" : "=v"(f) : "v"(rev));
      asm("v_sin_f32 %0, %1" : "=v"(sn) : "v"(f));
      asm("v_cos_f32 %0, %1" : "=v"(cs) : "v"(f));
      T2[(size_t)c * HALF + x] = make_float2(cs, -sn);
    }
    return;
  }
  if (bid >= 32) {                    // ---- A twiddle rows (parity layout) ----
    int idx = bid - 32;               // 0..383 ; row idx = par*192 + t
    int y = 2 * (idx % 192) + (idx / 192);
    if (tid < 96) {
      int r0 = tid * 4;
      union { __hip_bfloat16 h[4]; ushort4 v; } uc, us;
#pragma unroll
      for (int j = 0; j < 4; ++j) {
        int m = (y * (r0 + j)) % DIM;
        float s, c;
        sincosf((TWO_PI / (float)DIM) * (float)m, &s, &c);
        uc.h[j] = __float2bfloat16(c);
        us.h[j] = __float2bfloat16(s);
      }
      *(ushort4*)(A + (size_t)idx * KG + r0)        = uc.v;
      *(ushort4*)(A + (size_t)idx * KG + HALF + r0) = us.v;
    }
    return;
  }

  // ---- router + build, batch b = bid ----
  int b = bid;
  __shared__ int cnt[DIM];
  __shared__ int base[DIM];
  __shared__ int wsum[4];
  __shared__ int sel_i[2];
  __shared__ float sel_f[2];
  float* part   = (float*)cnt;
  float* logits = (float*)base;

  {
    int e = tid & 63, q = tid >> 6;
    const float* c = cls + b * DIM + q * 192;
    const float* w = W + e * DIM + q * 192;
    float acc = 0.f;
#pragma unroll 4
    for (int i = 0; i < 192; i += 4) {
      float4 cv4 = *(const float4*)(c + i);
      float4 wv4 = *(const float4*)(w + i);
      acc += cv4.x * wv4.x + cv4.y * wv4.y + cv4.z * wv4.z + cv4.w * wv4.w;
    }
    part[q * 64 + e] = acc;
    __syncthreads();
    if (tid < NE)
      logits[tid] = part[tid] + part[64 + tid] + part[128 + tid] + part[192 + tid] + bias[tid];
    __syncthreads();
    if (tid == 0) {
      int i0 = 0; float l0 = logits[0];
      for (int i = 1; i < NE; ++i) { float v = logits[i]; if (v > l0) { l0 = v; i0 = i; } }
      int i1 = -1; float l1 = -3.4e38f;
      for (int i = 0; i < NE; ++i) {
        if (i == i0) continue;
        float v = logits[i]; if (v > l1) { l1 = v; i1 = i; }
      }
      float w0 = 1.f / (1.f + expf(l1 - l0));
      sel_i[0] = i0; sel_i[1] = i1;
      sel_f[0] = w0; sel_f[1] = 1.f - w0;
    }
    __syncthreads();
  }
  int e0 = sel_i[0], e1 = sel_i[1];
  float w0 = sel_f[0], w1 = sel_f[1];

  for (int i = tid; i < DIM; i += 256) cnt[i] = 0;
  __syncthreads();
  for (int k = tid; k < 2 * NFRQ; k += 256) {
    int t = k >> 11, j = k & (NFRQ - 1);
    int e = t ? e1 : e0;
    int f = lidx[e * NFRQ + j];
    atomicAdd(&cnt[f / DIM], 1);
  }
  __syncthreads();
  {  // parallel exclusive scan of cnt[768]: 3 per thread
    int s0 = cnt[3 * tid], s1 = cnt[3 * tid + 1], s2 = cnt[3 * tid + 2];
    int sum = s0 + s1 + s2;
    int lane = tid & 63, wid = tid >> 6;
    int v = sum;
#pragma unroll
    for (int d = 1; d < 64; d <<= 1) {
      int u = __shfl_up(v, d);
      if (lane >= d) v += u;
    }
    if (lane == 63) wsum[wid] = v;
    __syncthreads();
    int woff = 0;
#pragma unroll
    for (int w = 0; w < 4; ++w) if (w < wid) woff += wsum[w];
    int excl = woff + v - sum;
    int* rsg = row_start + b * (DIM + 1);
    base[3 * tid]     = excl;
    base[3 * tid + 1] = excl + s0;
    base[3 * tid + 2] = excl + s0 + s1;
    rsg[3 * tid]     = excl;
    rsg[3 * tid + 1] = excl + s0;
    rsg[3 * tid + 2] = excl + s0 + s1;
    if (tid == 255) rsg[DIM] = excl + sum;   // == 4096
  }
  __syncthreads();
  for (int i = tid; i < DIM; i += 256) cnt[i] = 0;
  __syncthreads();
  for (int k = tid; k < 2 * NFRQ; k += 256) {
    int t = k >> 11, j = k & (NFRQ - 1);
    int e = t ? e1 : e0;
    float w = t ? w1 : w0;
    int f = lidx[e * NFRQ + j];
    int r = f / DIM, c = f - r * DIM;
    int pos = base[r] + atomicAdd(&cnt[r], 1);
    s_cv[b * 4096 + pos] = make_float2(__uint_as_float((unsigned)c * 3072u),
                                       coeff[e * NFRQ + j] * w * SCALE);
  }
}

// ---------------------------------------------------------------------------
// Kernel B (v3): stage-1 SpMM, x split 3-ways (1 float4/lane/nz), 4 nz
// streams/wave (2 pairs x {r, r+384}) for 4x MLP, 32 pair-rows per block so
// the flush writes COMPLETE 64B lines (kills the 2x write amplification).
// LDS [4][32][132] (+4 pad): compute writes conflict-free, flush gather 2-way.
// Grid (12 rg, 3 xg, 32 b) = 1152 blocks.
// ---------------------------------------------------------------------------
__global__ __launch_bounds__(256) void stage1_kernel(const int* __restrict__ row_start,
                                                     const float2* __restrict__ s_cv,
                                                     const float2* __restrict__ T2,
                                                     __hip_bfloat16* __restrict__ BT) {
  int b = blockIdx.z;
  int xg = blockIdx.y;                  // 0..2 (x-chunk of 128)
  int rg = blockIdx.x;                  // 0..11 (32 pair-rows)
  int tid = threadIdx.x;
  int lane = tid & 63, w = tid >> 6;
  __shared__ __hip_bfloat16 lds[4][32][132];   // 0:ReP 1:ImP 2:ReM 3:ImM
  const int* rs = row_start + b * (DIM + 1);
  const float2* cv = s_cv + b * 4096;
  int rowBase = rg * 32;
  size_t xbyte = (size_t)xg * 1024 + (size_t)lane * 16;   // float4 per lane

  for (int rr = 0; rr < 4; ++rr) {
    int slot0 = w * 8 + 2 * rr;
    int p0 = rowBase + slot0;
    int sA0 = rs[p0],       nA0 = rs[p0 + 1]   - sA0;
    int sB0 = rs[p0 + 384], nB0 = rs[p0 + 385] - sB0;
    int sA1 = rs[p0 + 1],   nA1 = rs[p0 + 2]   - sA1;
    int sB1 = rs[p0 + 385], nB1 = rs[p0 + 386] - sB1;
    int kmax = nA0 > nB0 ? nA0 : nB0;
    int km2  = nA1 > nB1 ? nA1 : nB1;
    if (km2 > kmax) kmax = km2;
    float a0[4] = {0,0,0,0}, b0[4] = {0,0,0,0};
    float a1[4] = {0,0,0,0}, b1[4] = {0,0,0,0};
    for (int k = 0; k < kmax; ++k) {           // 4 independent streams
      if (k < nA0) {
        float2 c = cv[sA0 + k];
        float4 t = *(const float4*)((const char*)T2 + (size_t)__float_as_uint(c.x) + xbyte);
        a0[0] += c.y * t.x; a0[1] += c.y * t.y; a0[2] += c.y * t.z; a0[3] += c.y * t.w;
      }
      if (k < nB0) {
        float2 c = cv[sB0 + k];
        float4 t = *(const float4*)((const char*)T2 + (size_t)__float_as_uint(c.x) + xbyte);
        b0[0] += c.y * t.x; b0[1] += c.y * t.y; b0[2] += c.y * t.z; b0[3] += c.y * t.w;
      }
      if (k < nA1) {
        float2 c = cv[sA1 + k];
        float4 t = *(const float4*)((const char*)T2 + (size_t)__float_as_uint(c.x) + xbyte);
        a1[0] += c.y * t.x; a1[1] += c.y * t.y; a1[2] += c.y * t.z; a1[3] += c.y * t.w;
      }
      if (k < nB1) {
        float2 c = cv[sB1 + k];
        float4 t = *(const float4*)((const char*)T2 + (size_t)__float_as_uint(c.x) + xbyte);
        b1[0] += c.y * t.x; b1[1] += c.y * t.y; b1[2] += c.y * t.z; b1[3] += c.y * t.w;
      }
    }
    // combine P = A+B, M = A-B; t layout: (cos,-sin) for x0=2*lane, x1=2*lane+1
    int xl = 2 * lane;
    union { __hip_bfloat16 h[2]; unsigned u; } u0;
#pragma unroll
    for (int s = 0; s < 2; ++s) {
      const float* aa = s ? a1 : a0;
      const float* bb = s ? b1 : b0;
      int slot = slot0 + s;
      u0.h[0] = __float2bfloat16(aa[0] + bb[0]); u0.h[1] = __float2bfloat16(aa[2] + bb[2]);
      *(unsigned*)&lds[0][slot][xl] = u0.u;                       // ReP
      u0.h[0] = __float2bfloat16(aa[1] + bb[1]); u0.h[1] = __float2bfloat16(aa[3] + bb[3]);
      *(unsigned*)&lds[1][slot][xl] = u0.u;                       // -ImP
      u0.h[0] = __float2bfloat16(aa[0] - bb[0]); u0.h[1] = __float2bfloat16(aa[2] - bb[2]);
      *(unsigned*)&lds[2][slot][xl] = u0.u;                       // ReM
      u0.h[0] = __float2bfloat16(aa[1] - bb[1]); u0.h[1] = __float2bfloat16(aa[3] - bb[3]);
      *(unsigned*)&lds[3][slot][xl] = u0.u;                       // -ImM
    }
  }
  __syncthreads();
  // flush: 4 arrays x 128 x = 512 tasks; each writes one FULL 64B line
  for (int i = tid; i < 512; i += 256) {
    int a = i >> 7, x = i & 127;
    union { ushort h[32]; uint4 v[4]; } u;
#pragma unroll
    for (int k = 0; k < 32; ++k) u.h[k] = *(const ushort*)&lds[a][k][x];
    __hip_bfloat16* dst = BT + ((size_t)(b * HALF + xg * 128 + x)) * KROW + a * HALF + rowBase;
#pragma unroll
    for (int q = 0; q < 4; ++q) *(uint4*)(dst + q * 8) = u.v[q];
  }
}

// ---------------------------------------------------------------------------
// Kernel C: nyq blocks (bid<128) + parity quadrant GEMM  [unchanged from R12]
// BK=64, 12 steps, double-buffer + __syncthreads, 8-slot XOR swizzle.
// ---------------------------------------------------------------------------
__device__ inline void gload_lds16(const void* g, void* l) {
  __builtin_amdgcn_global_load_lds((const __attribute__((address_space(1))) void*)g,
                                   (__attribute__((address_space(3))) void*)l, 16, 0, 0);
}

__global__ __launch_bounds__(256) void gemm_kernel(const __hip_bfloat16* __restrict__ A,
                                                   const __hip_bfloat16* __restrict__ BT,
                                                   const int* __restrict__ row_start,
                                                   const float2* __restrict__ s_cv,
                                                   float* __restrict__ C) {
  int bid = blockIdx.x;
  int tid = threadIdx.x;
  __shared__ __align__(16) __hip_bfloat16 As[2][64 * 64];   // 16KB
  __shared__ __align__(16) __hip_bfloat16 Bs[2][64 * 64];   // 16KB

  if (bid < 4 * NB) {                 // ---- Nyquist blocks ----
    int slice = bid & 3, b = bid >> 2;
    float* ob = C + (size_t)b * DIM * DIM;
    if (slice == 3) {                 // row y=384: sum_rp (-1)^rp ReP[rp,x]
      for (int x = tid; x < HALF; x += 256) {
        const __hip_bfloat16* btx = BT + ((size_t)(b * HALF + x)) * KROW;
        float acc = 0.f;
        for (int r = 0; r < HALF; r += 8) {
          union { uint4 v4; __hip_bfloat16 h[8]; } u;
          u.v4 = *(const uint4*)(btx + r);
#pragma unroll
          for (int q = 0; q < 8; ++q) {
            float v = __bfloat162float(u.h[q]);
            acc += (q & 1) ? -v : v;
          }
        }
        int xm = x ? DIM - x : 0;
        ob[(size_t)HALF * DIM + x]  = acc;
        ob[(size_t)HALF * DIM + xm] = acc;
      }
      return;
    }
    // slices 0..2: column x=384
    float* Re384 = (float*)As;        // reuse LDS
    const int* rs = row_start + b * (DIM + 1);
    const float2* cv = s_cv + b * 4096;
    for (int r = tid; r < DIM; r += 256) {
      int s = rs[r], e = rs[r + 1];
      float acc = 0.f;
      for (int p = s; p < e; ++p) {
        float2 c = cv[p];
        int ci = (int)(__float_as_uint(c.x) / 3072u);
        acc += (ci & 1) ? -c.y : c.y;
      }
      Re384[r] = acc;
    }
    __syncthreads();
    int y = slice * 129 + tid;
    if (tid < 129 && y <= HALF) {
      float yf = (float)y;
      float a0 = 0.f, a1 = 0.f, a2 = 0.f, a3 = 0.f;
      for (int r = 0; r < DIM; r += 4) {
        float f0, f1, f2, f3, c0, c1, c2, c3;
        float v0 = (yf * (float)(r + 0)) * INV768;
        float v1 = (yf * (float)(r + 1)) * INV768;
        float v2 = (yf * (float)(r + 2)) * INV768;
        float v3 = (yf * (float)(r + 3)) * INV768;
        asm("v_fract_f32 %0, %1" : "=v"(f0) : "v"(v0));
        asm("v_fract_f32 %0, %1" : "=v"(f1) : "v"(v1));
        asm("v_fract_f32 %0, %1" : "=v"(f2) : "v"(v2));
        asm("v_fract_f32 %0, %1" : "=v"(f3) : "v"(v3));
        asm("v_cos_f32 %0, %1" : "=v"(c0) : "v"(f0));
        asm("v_cos_f32 %0, %1" : "=v"(c1) : "v"(f1));
        asm("v_cos_f32 %0, %1" : "=v"(c2) : "v"(f2));
        asm("v_cos_f32 %0, %1" : "=v"(c3) : "v"(f3));
        a0 += Re384[r + 0] * c0;
        a1 += Re384[r + 1] * c1;
        a2 += Re384[r + 2] * c2;
        a3 += Re384[r + 3] * c3;
      }
      float acc = (a0 + a1) + (a2 + a3);
      int ym = y ? DIM - y : 0;
      ob[(size_t)y  * DIM + HALF] = acc;
      ob[(size_t)ym * DIM + HALF] = acc;
    }
    return;
  }

  // ---- GEMM blocks: 1152 = 8*144; 36 tiles/batch = 2 par x 6 bx x 3 by ----
  int gbid = bid - 4 * NB;
  int swz = (gbid & 7) * 144 + (gbid >> 3);
  int b = swz / 36; int rem = swz - b * 36;
  int par = rem / 18; int r2 = rem - par * 18;
  int bx = r2 / 3, by = r2 % 3;

  float* Cp = C + (size_t)b * DIM * DIM;
  int y0 = by * 64, x0 = bx * 64;     // y0 in t-space [0,192)

  int wv = tid >> 6, lane = tid & 63;
  int wr = wv >> 1, wc = wv & 1;      // wave: 32x32 sub-tile
  int lhi = lane >> 4, llo = lane & 15;

  int c0 = tid, c1 = tid + 256;
  int row0 = c0 >> 3, row1 = c1 >> 3;
  int so0 = (((c0 & 7) ^ (row0 & 7))) * 8;
  int so1 = (((c1 & 7) ^ (row1 & 7))) * 8;

  f32x4 acc1[2][2] = {};
  f32x4 acc2[2][2] = {};

  const __hip_bfloat16* A0 = A  + ((size_t)(par * 192 + y0 + row0)) * KG + so0;
  const __hip_bfloat16* A1 = A  + ((size_t)(par * 192 + y0 + row1)) * KG + so1;
  const __hip_bfloat16* B0 = BT + ((size_t)(b * HALF + x0 + row0)) * KROW + par * KG + so0;
  const __hip_bfloat16* B1 = BT + ((size_t)(b * HALF + x0 + row1)) * KROW + par * KG + so1;

  gload_lds16(A0, As[0] + c0 * 8);
  gload_lds16(A1, As[0] + c1 * 8);
  gload_lds16(B0, Bs[0] + c0 * 8);
  gload_lds16(B1, Bs[0] + c1 * 8);
  __syncthreads();

  auto step = [&](int t, f32x4 (&acc)[2][2], bool last) {
    int cur = t & 1;
    if (!last) {
      int ktn = (t + 1) * 64;
      gload_lds16(A0 + ktn, As[cur ^ 1] + c0 * 8);
      gload_lds16(A1 + ktn, As[cur ^ 1] + c1 * 8);
      gload_lds16(B0 + ktn, Bs[cur ^ 1] + c0 * 8);
      gload_lds16(B1 + ktn, Bs[cur ^ 1] + c1 * 8);
    }
    bf16x8 af[2][2], bfr[2][2];
#pragma unroll
    for (int i = 0; i < 2; ++i)
#pragma unroll
      for (int kh = 0; kh < 2; ++kh) {
        int row = wr * 32 + i * 16 + llo;
        int phys = ((lhi + 4 * kh) ^ (llo & 7)) * 8;
        af[i][kh] = *(const bf16x8*)(As[cur] + row * 64 + phys);
      }
#pragma unroll
    for (int j = 0; j < 2; ++j)
#pragma unroll
      for (int kh = 0; kh < 2; ++kh) {
        int row = wc * 32 + j * 16 + llo;
        int phys = ((lhi + 4 * kh) ^ (llo & 7)) * 8;
        bfr[j][kh] = *(const bf16x8*)(Bs[cur] + row * 64 + phys);
      }
#pragma unroll
    for (int kh = 0; kh < 2; ++kh)
#pragma unroll
      for (int i = 0; i < 2; ++i)
#pragma unroll
        for (int j = 0; j < 2; ++j)
          acc[i][j] = __builtin_amdgcn_mfma_f32_16x16x32_bf16(af[i][kh], bfr[j][kh],
                                                              acc[i][j], 0, 0, 0);
    if (!last) __syncthreads();
  };

  for (int t = 0; t < 6; ++t)  step(t, acc1, false);       // cos half
  for (int t = 6; t < 12; ++t) step(t, acc2, t == 11);     // sin half

#pragma unroll
  for (int i = 0; i < 2; ++i) {
#pragma unroll
    for (int j = 0; j < 2; ++j) {
      int x = x0 + wc * 32 + j * 16 + llo;
      int xm = x ? DIM - x : 0;
#pragma unroll
      for (int q = 0; q < 4; ++q) {
        int tt = y0 + wr * 32 + i * 16 + lhi * 4 + q;
        int y = 2 * tt + par;
        int ym = y ? DIM - y : 0;
        float c1 = acc1[i][j][q], c2 = acc2[i][j][q];
        float vd = c1 + c2;
        float vs = c1 - c2;
        Cp[(size_t)y  * DIM + x]  = vd;
        Cp[(size_t)ym * DIM + xm] = vd;
        Cp[(size_t)y  * DIM + xm] = vs;
        Cp[(size_t)ym * DIM + x]  = vs;
      }
    }
  }
}

// ---------------------------------------------------------------------------
extern "C" void kernel_launch(void* const* d_in, const int* in_sizes, int n_in,
                              void* d_out, int out_size, void* d_ws, size_t ws_size,
                              hipStream_t stream) {
  const float* cls   = (const float*)d_in[0];
  const float* Wr    = (const float*)d_in[1];
  const float* br    = (const float*)d_in[2];
  const float* coeff = (const float*)d_in[3];
  const int*   lidx  = (const int*)d_in[4];
  float* out = (float*)d_out;

  char* ws = (char*)d_ws;
  int*    row_start = (int*)(ws + 0);           //    98,432
  float2* s_cv      = (float2*)(ws + 98944);    // 1,048,576 (ends 1,147,520)
  __hip_bfloat16* A  = (__hip_bfloat16*)(ws + 1147520);  // 589,824 (ends 1,737,344)
  float2* T2        = (float2*)(ws + 1737344);  // 2,359,296 (ends 4,096,640)
  __hip_bfloat16* BT = (__hip_bfloat16*)(ws + 4096640);  // 37,748,736 (~42 MB)

  prep_kernel<<<32 + 384 + DIM, 256, 0, stream>>>(cls, Wr, br, coeff, lidx,
                                                  row_start, s_cv, A, T2);
  stage1_kernel<<<dim3(12, 3, NB), 256, 0, stream>>>(row_start, s_cv, T2, BT);
  gemm_kernel<<<4 * NB + 1152, 256, 0, stream>>>(A, BT, row_start, s_cv, out);
}

// Round 14
// 124.532 us; speedup vs baseline: 1.1784x; 1.1784x over previous
//
#include <hip/hip_runtime.h>
#include <hip/hip_bf16.h>

#define DIM 768
#define NE 64
#define NFRQ 2048
#define NB 32
#define HALF 384                // computed quadrant extent (y,x in [0,384))
#define KROW 1536               // BT per-x row elems: [ReP|-ImP|ReM|-ImM] x 384
#define KG 768                  // GEMM K per parity (384 cos + 384 sin)
#define TWO_PI 6.283185307179586f
#define INV768 (1.0f / 768.0f)
#define SCALE (300.0f / (float)(DIM * DIM))   // ALPHA / (dim*dim), folded into values

typedef __attribute__((ext_vector_type(8))) short bf16x8;   // 8 bf16 (4 VGPRs)
typedef __attribute__((ext_vector_type(4))) float f32x4;    // MFMA accumulator

// ---------------------------------------------------------------------------
// Kernel A "prep" (one launch, 3 roles by blockIdx)  [unchanged from R12]
// ---------------------------------------------------------------------------
__global__ __launch_bounds__(256) void prep_kernel(const float* __restrict__ cls,
                                                   const float* __restrict__ W,
                                                   const float* __restrict__ bias,
                                                   const float* __restrict__ coeff,
                                                   const int* __restrict__ lidx,
                                                   int* __restrict__ row_start,
                                                   float2* __restrict__ s_cv,
                                                   __hip_bfloat16* __restrict__ A,
                                                   float2* __restrict__ T2) {
  int bid = blockIdx.x;
  int tid = threadIdx.x;

  if (bid >= 32 + 2 * 192) {          // ---- T2 rows ----
    int c = bid - (32 + 2 * 192);     // 0..767
    for (int x = tid; x < HALF; x += 256) {
      float prod = (float)(c * x);    // < 2^24, exact
      float f, sn, cs;
      float rev = prod * INV768;
      asm("v_fract_f32 %0, %1" : "=v"(f) : "v"(rev));
      asm("v_sin_f32 %0, %1" : "=v"(sn) : "v"(f));
      asm("v_cos_f32 %0, %1" : "=v"(cs) : "v"(f));
      T2[(size_t)c * HALF + x] = make_float2(cs, -sn);
    }
    return;
  }
  if (bid >= 32) {                    // ---- A twiddle rows (parity layout) ----
    int idx = bid - 32;               // 0..383 ; row idx = par*192 + t
    int y = 2 * (idx % 192) + (idx / 192);
    if (tid < 96) {
      int r0 = tid * 4;
      union { __hip_bfloat16 h[4]; ushort4 v; } uc, us;
#pragma unroll
      for (int j = 0; j < 4; ++j) {
        int m = (y * (r0 + j)) % DIM;
        float s, c;
        sincosf((TWO_PI / (float)DIM) * (float)m, &s, &c);
        uc.h[j] = __float2bfloat16(c);
        us.h[j] = __float2bfloat16(s);
      }
      *(ushort4*)(A + (size_t)idx * KG + r0)        = uc.v;
      *(ushort4*)(A + (size_t)idx * KG + HALF + r0) = us.v;
    }
    return;
  }

  // ---- router + build, batch b = bid ----
  int b = bid;
  __shared__ int cnt[DIM];
  __shared__ int base[DIM];
  __shared__ int wsum[4];
  __shared__ int sel_i[2];
  __shared__ float sel_f[2];
  float* part   = (float*)cnt;
  float* logits = (float*)base;

  {
    int e = tid & 63, q = tid >> 6;
    const float* c = cls + b * DIM + q * 192;
    const float* w = W + e * DIM + q * 192;
    float acc = 0.f;
#pragma unroll 4
    for (int i = 0; i < 192; i += 4) {
      float4 cv4 = *(const float4*)(c + i);
      float4 wv4 = *(const float4*)(w + i);
      acc += cv4.x * wv4.x + cv4.y * wv4.y + cv4.z * wv4.z + cv4.w * wv4.w;
    }
    part[q * 64 + e] = acc;
    __syncthreads();
    if (tid < NE)
      logits[tid] = part[tid] + part[64 + tid] + part[128 + tid] + part[192 + tid] + bias[tid];
    __syncthreads();
    if (tid == 0) {
      int i0 = 0; float l0 = logits[0];
      for (int i = 1; i < NE; ++i) { float v = logits[i]; if (v > l0) { l0 = v; i0 = i; } }
      int i1 = -1; float l1 = -3.4e38f;
      for (int i = 0; i < NE; ++i) {
        if (i == i0) continue;
        float v = logits[i]; if (v > l1) { l1 = v; i1 = i; }
      }
      float w0 = 1.f / (1.f + expf(l1 - l0));
      sel_i[0] = i0; sel_i[1] = i1;
      sel_f[0] = w0; sel_f[1] = 1.f - w0;
    }
    __syncthreads();
  }
  int e0 = sel_i[0], e1 = sel_i[1];
  float w0 = sel_f[0], w1 = sel_f[1];

  for (int i = tid; i < DIM; i += 256) cnt[i] = 0;
  __syncthreads();
  for (int k = tid; k < 2 * NFRQ; k += 256) {
    int t = k >> 11, j = k & (NFRQ - 1);
    int e = t ? e1 : e0;
    int f = lidx[e * NFRQ + j];
    atomicAdd(&cnt[f / DIM], 1);
  }
  __syncthreads();
  {  // parallel exclusive scan of cnt[768]: 3 per thread
    int s0 = cnt[3 * tid], s1 = cnt[3 * tid + 1], s2 = cnt[3 * tid + 2];
    int sum = s0 + s1 + s2;
    int lane = tid & 63, wid = tid >> 6;
    int v = sum;
#pragma unroll
    for (int d = 1; d < 64; d <<= 1) {
      int u = __shfl_up(v, d);
      if (lane >= d) v += u;
    }
    if (lane == 63) wsum[wid] = v;
    __syncthreads();
    int woff = 0;
#pragma unroll
    for (int w = 0; w < 4; ++w) if (w < wid) woff += wsum[w];
    int excl = woff + v - sum;
    int* rsg = row_start + b * (DIM + 1);
    base[3 * tid]     = excl;
    base[3 * tid + 1] = excl + s0;
    base[3 * tid + 2] = excl + s0 + s1;
    rsg[3 * tid]     = excl;
    rsg[3 * tid + 1] = excl + s0;
    rsg[3 * tid + 2] = excl + s0 + s1;
    if (tid == 255) rsg[DIM] = excl + sum;   // == 4096
  }
  __syncthreads();
  for (int i = tid; i < DIM; i += 256) cnt[i] = 0;
  __syncthreads();
  for (int k = tid; k < 2 * NFRQ; k += 256) {
    int t = k >> 11, j = k & (NFRQ - 1);
    int e = t ? e1 : e0;
    float w = t ? w1 : w0;
    int f = lidx[e * NFRQ + j];
    int r = f / DIM, c = f - r * DIM;
    int pos = base[r] + atomicAdd(&cnt[r], 1);
    s_cv[b * 4096 + pos] = make_float2(__uint_as_float((unsigned)c * 3072u),
                                       coeff[e * NFRQ + j] * w * SCALE);
  }
}

// ---------------------------------------------------------------------------
// Kernel B (v4): stage-1 SpMM. Keeps v3's full-64B-line flush (32 pair-rows
// per block) but 8 waves x 8 CONCURRENT streams (4 pairs x {r, r+384}) per
// wave -> serial depth ~kmax(8 Poisson) ~= 11 instead of 36, 2x streams.
// LDS [4][32][132]; flush = 512 tasks, one full line each.
// Grid (12 rg, 3 xg, 32 b) = 1152 blocks x 512 threads.
// ---------------------------------------------------------------------------
__global__ __launch_bounds__(512) void stage1_kernel(const int* __restrict__ row_start,
                                                     const float2* __restrict__ s_cv,
                                                     const float2* __restrict__ T2,
                                                     __hip_bfloat16* __restrict__ BT) {
  int b = blockIdx.z;
  int xg = blockIdx.y;                  // 0..2 (x-chunk of 128)
  int rg = blockIdx.x;                  // 0..11 (32 pair-rows)
  int tid = threadIdx.x;                // 512
  int lane = tid & 63, w = tid >> 6;    // w in 0..7
  __shared__ __hip_bfloat16 lds[4][32][132];   // 0:ReP 1:ImP 2:ReM 3:ImM
  const int* rs = row_start + b * (DIM + 1);
  const float2* cv = s_cv + b * 4096;
  int rowBase = rg * 32;
  size_t xbyte = (size_t)xg * 1024 + (size_t)lane * 16;   // float4 per lane

  // wave w owns pairs pbase..pbase+3; 8 streams: s -> row pbase+(s>>1)+(s&1)*384
  int pbase = rowBase + w * 4;
  int sstart[8], scount[8];
#pragma unroll
  for (int s = 0; s < 8; ++s) {
    int row = pbase + (s >> 1) + (s & 1) * 384;
    int st = rs[row];
    sstart[s] = st;
    scount[s] = rs[row + 1] - st;
  }
  int kmax = 0;
#pragma unroll
  for (int s = 0; s < 8; ++s) kmax = scount[s] > kmax ? scount[s] : kmax;

  float acc[8][4];
#pragma unroll
  for (int s = 0; s < 8; ++s) { acc[s][0] = acc[s][1] = acc[s][2] = acc[s][3] = 0.f; }

  for (int k = 0; k < kmax; ++k) {      // 8 independent guarded streams
#pragma unroll
    for (int s = 0; s < 8; ++s) {
      if (k < scount[s]) {              // wave-uniform guard
        float2 c = cv[sstart[s] + k];
        float4 t = *(const float4*)((const char*)T2 + (size_t)__float_as_uint(c.x) + xbyte);
        acc[s][0] += c.y * t.x; acc[s][1] += c.y * t.y;
        acc[s][2] += c.y * t.z; acc[s][3] += c.y * t.w;
      }
    }
  }

  // combine P = A+B, M = A-B per pair q: A = stream 2q, B = stream 2q+1
  // t layout: x0=xg*128+2*lane (cos,-sin), x1=x0+1 -> acc[.]={re0,-im0,re1,-im1}
  int xl = 2 * lane;
  union { __hip_bfloat16 h[2]; unsigned u; } u0;
#pragma unroll
  for (int q = 0; q < 4; ++q) {
    int slot = w * 4 + q;
    const float* aa = acc[2 * q];
    const float* bb = acc[2 * q + 1];
    u0.h[0] = __float2bfloat16(aa[0] + bb[0]); u0.h[1] = __float2bfloat16(aa[2] + bb[2]);
    *(unsigned*)&lds[0][slot][xl] = u0.u;                       // ReP
    u0.h[0] = __float2bfloat16(aa[1] + bb[1]); u0.h[1] = __float2bfloat16(aa[3] + bb[3]);
    *(unsigned*)&lds[1][slot][xl] = u0.u;                       // -ImP
    u0.h[0] = __float2bfloat16(aa[0] - bb[0]); u0.h[1] = __float2bfloat16(aa[2] - bb[2]);
    *(unsigned*)&lds[2][slot][xl] = u0.u;                       // ReM
    u0.h[0] = __float2bfloat16(aa[1] - bb[1]); u0.h[1] = __float2bfloat16(aa[3] - bb[3]);
    *(unsigned*)&lds[3][slot][xl] = u0.u;                       // -ImM
  }
  __syncthreads();
  // flush: 4 arrays x 128 x = 512 tasks = 1/thread; each one FULL 64B line
  {
    int a = tid >> 7, x = tid & 127;
    union { ushort h[32]; uint4 v[4]; } u;
#pragma unroll
    for (int k = 0; k < 32; ++k) u.h[k] = *(const ushort*)&lds[a][k][x];
    __hip_bfloat16* dst = BT + ((size_t)(b * HALF + xg * 128 + x)) * KROW + a * HALF + rowBase;
#pragma unroll
    for (int q = 0; q < 4; ++q) *(uint4*)(dst + q * 8) = u.v[q];
  }
}

// ---------------------------------------------------------------------------
// Kernel C: nyq blocks (bid<128) + parity quadrant GEMM  [unchanged from R12]
// BK=64, 12 steps, double-buffer + __syncthreads, 8-slot XOR swizzle.
// ---------------------------------------------------------------------------
__device__ inline void gload_lds16(const void* g, void* l) {
  __builtin_amdgcn_global_load_lds((const __attribute__((address_space(1))) void*)g,
                                   (__attribute__((address_space(3))) void*)l, 16, 0, 0);
}

__global__ __launch_bounds__(256) void gemm_kernel(const __hip_bfloat16* __restrict__ A,
                                                   const __hip_bfloat16* __restrict__ BT,
                                                   const int* __restrict__ row_start,
                                                   const float2* __restrict__ s_cv,
                                                   float* __restrict__ C) {
  int bid = blockIdx.x;
  int tid = threadIdx.x;
  __shared__ __align__(16) __hip_bfloat16 As[2][64 * 64];   // 16KB
  __shared__ __align__(16) __hip_bfloat16 Bs[2][64 * 64];   // 16KB

  if (bid < 4 * NB) {                 // ---- Nyquist blocks ----
    int slice = bid & 3, b = bid >> 2;
    float* ob = C + (size_t)b * DIM * DIM;
    if (slice == 3) {                 // row y=384: sum_rp (-1)^rp ReP[rp,x]
      for (int x = tid; x < HALF; x += 256) {
        const __hip_bfloat16* btx = BT + ((size_t)(b * HALF + x)) * KROW;
        float acc = 0.f;
        for (int r = 0; r < HALF; r += 8) {
          union { uint4 v4; __hip_bfloat16 h[8]; } u;
          u.v4 = *(const uint4*)(btx + r);
#pragma unroll
          for (int q = 0; q < 8; ++q) {
            float v = __bfloat162float(u.h[q]);
            acc += (q & 1) ? -v : v;
          }
        }
        int xm = x ? DIM - x : 0;
        ob[(size_t)HALF * DIM + x]  = acc;
        ob[(size_t)HALF * DIM + xm] = acc;
      }
      return;
    }
    // slices 0..2: column x=384
    float* Re384 = (float*)As;        // reuse LDS
    const int* rs = row_start + b * (DIM + 1);
    const float2* cv = s_cv + b * 4096;
    for (int r = tid; r < DIM; r += 256) {
      int s = rs[r], e = rs[r + 1];
      float acc = 0.f;
      for (int p = s; p < e; ++p) {
        float2 c = cv[p];
        int ci = (int)(__float_as_uint(c.x) / 3072u);
        acc += (ci & 1) ? -c.y : c.y;
      }
      Re384[r] = acc;
    }
    __syncthreads();
    int y = slice * 129 + tid;
    if (tid < 129 && y <= HALF) {
      float yf = (float)y;
      float a0 = 0.f, a1 = 0.f, a2 = 0.f, a3 = 0.f;
      for (int r = 0; r < DIM; r += 4) {
        float f0, f1, f2, f3, c0, c1, c2, c3;
        float v0 = (yf * (float)(r + 0)) * INV768;
        float v1 = (yf * (float)(r + 1)) * INV768;
        float v2 = (yf * (float)(r + 2)) * INV768;
        float v3 = (yf * (float)(r + 3)) * INV768;
        asm("v_fract_f32 %0, %1" : "=v"(f0) : "v"(v0));
        asm("v_fract_f32 %0, %1" : "=v"(f1) : "v"(v1));
        asm("v_fract_f32 %0, %1" : "=v"(f2) : "v"(v2));
        asm("v_fract_f32 %0, %1" : "=v"(f3) : "v"(v3));
        asm("v_cos_f32 %0, %1" : "=v"(c0) : "v"(f0));
        asm("v_cos_f32 %0, %1" : "=v"(c1) : "v"(f1));
        asm("v_cos_f32 %0, %1" : "=v"(c2) : "v"(f2));
        asm("v_cos_f32 %0, %1" : "=v"(c3) : "v"(f3));
        a0 += Re384[r + 0] * c0;
        a1 += Re384[r + 1] * c1;
        a2 += Re384[r + 2] * c2;
        a3 += Re384[r + 3] * c3;
      }
      float acc = (a0 + a1) + (a2 + a3);
      int ym = y ? DIM - y : 0;
      ob[(size_t)y  * DIM + HALF] = acc;
      ob[(size_t)ym * DIM + HALF] = acc;
    }
    return;
  }

  // ---- GEMM blocks: 1152 = 8*144; 36 tiles/batch = 2 par x 6 bx x 3 by ----
  int gbid = bid - 4 * NB;
  int swz = (gbid & 7) * 144 + (gbid >> 3);
  int b = swz / 36; int rem = swz - b * 36;
  int par = rem / 18; int r2 = rem - par * 18;
  int bx = r2 / 3, by = r2 % 3;

  float* Cp = C + (size_t)b * DIM * DIM;
  int y0 = by * 64, x0 = bx * 64;     // y0 in t-space [0,192)

  int wv = tid >> 6, lane = tid & 63;
  int wr = wv >> 1, wc = wv & 1;      // wave: 32x32 sub-tile
  int lhi = lane >> 4, llo = lane & 15;

  int c0 = tid, c1 = tid + 256;
  int row0 = c0 >> 3, row1 = c1 >> 3;
  int so0 = (((c0 & 7) ^ (row0 & 7))) * 8;
  int so1 = (((c1 & 7) ^ (row1 & 7))) * 8;

  f32x4 acc1[2][2] = {};
  f32x4 acc2[2][2] = {};

  const __hip_bfloat16* A0 = A  + ((size_t)(par * 192 + y0 + row0)) * KG + so0;
  const __hip_bfloat16* A1 = A  + ((size_t)(par * 192 + y0 + row1)) * KG + so1;
  const __hip_bfloat16* B0 = BT + ((size_t)(b * HALF + x0 + row0)) * KROW + par * KG + so0;
  const __hip_bfloat16* B1 = BT + ((size_t)(b * HALF + x0 + row1)) * KROW + par * KG + so1;

  gload_lds16(A0, As[0] + c0 * 8);
  gload_lds16(A1, As[0] + c1 * 8);
  gload_lds16(B0, Bs[0] + c0 * 8);
  gload_lds16(B1, Bs[0] + c1 * 8);
  __syncthreads();

  auto step = [&](int t, f32x4 (&acc)[2][2], bool last) {
    int cur = t & 1;
    if (!last) {
      int ktn = (t + 1) * 64;
      gload_lds16(A0 + ktn, As[cur ^ 1] + c0 * 8);
      gload_lds16(A1 + ktn, As[cur ^ 1] + c1 * 8);
      gload_lds16(B0 + ktn, Bs[cur ^ 1] + c0 * 8);
      gload_lds16(B1 + ktn, Bs[cur ^ 1] + c1 * 8);
    }
    bf16x8 af[2][2], bfr[2][2];
#pragma unroll
    for (int i = 0; i < 2; ++i)
#pragma unroll
      for (int kh = 0; kh < 2; ++kh) {
        int row = wr * 32 + i * 16 + llo;
        int phys = ((lhi + 4 * kh) ^ (llo & 7)) * 8;
        af[i][kh] = *(const bf16x8*)(As[cur] + row * 64 + phys);
      }
#pragma unroll
    for (int j = 0; j < 2; ++j)
#pragma unroll
      for (int kh = 0; kh < 2; ++kh) {
        int row = wc * 32 + j * 16 + llo;
        int phys = ((lhi + 4 * kh) ^ (llo & 7)) * 8;
        bfr[j][kh] = *(const bf16x8*)(Bs[cur] + row * 64 + phys);
      }
#pragma unroll
    for (int kh = 0; kh < 2; ++kh)
#pragma unroll
      for (int i = 0; i < 2; ++i)
#pragma unroll
        for (int j = 0; j < 2; ++j)
          acc[i][j] = __builtin_amdgcn_mfma_f32_16x16x32_bf16(af[i][kh], bfr[j][kh],
                                                              acc[i][j], 0, 0, 0);
    if (!last) __syncthreads();
  };

  for (int t = 0; t < 6; ++t)  step(t, acc1, false);       // cos half
  for (int t = 6; t < 12; ++t) step(t, acc2, t == 11);     // sin half

#pragma unroll
  for (int i = 0; i < 2; ++i) {
#pragma unroll
    for (int j = 0; j < 2; ++j) {
      int x = x0 + wc * 32 + j * 16 + llo;
      int xm = x ? DIM - x : 0;
#pragma unroll
      for (int q = 0; q < 4; ++q) {
        int tt = y0 + wr * 32 + i * 16 + lhi * 4 + q;
        int y = 2 * tt + par;
        int ym = y ? DIM - y : 0;
        float c1 = acc1[i][j][q], c2 = acc2[i][j][q];
        float vd = c1 + c2;
        float vs = c1 - c2;
        Cp[(size_t)y  * DIM + x]  = vd;
        Cp[(size_t)ym * DIM + xm] = vd;
        Cp[(size_t)y  * DIM + xm] = vs;
        Cp[(size_t)ym * DIM + x]  = vs;
      }
    }
  }
}

// ---------------------------------------------------------------------------
extern "C" void kernel_launch(void* const* d_in, const int* in_sizes, int n_in,
                              void* d_out, int out_size, void* d_ws, size_t ws_size,
                              hipStream_t stream) {
  const float* cls   = (const float*)d_in[0];
  const float* Wr    = (const float*)d_in[1];
  const float* br    = (const float*)d_in[2];
  const float* coeff = (const float*)d_in[3];
  const int*   lidx  = (const int*)d_in[4];
  float* out = (float*)d_out;

  char* ws = (char*)d_ws;
  int*    row_start = (int*)(ws + 0);           //    98,432
  float2* s_cv      = (float2*)(ws + 98944);    // 1,048,576 (ends 1,147,520)
  __hip_bfloat16* A  = (__hip_bfloat16*)(ws + 1147520);  // 589,824 (ends 1,737,344)
  float2* T2        = (float2*)(ws + 1737344);  // 2,359,296 (ends 4,096,640)
  __hip_bfloat16* BT = (__hip_bfloat16*)(ws + 4096640);  // 37,748,736 (~42 MB)

  prep_kernel<<<32 + 384 + DIM, 256, 0, stream>>>(cls, Wr, br, coeff, lidx,
                                                  row_start, s_cv, A, T2);
  stage1_kernel<<<dim3(12, 3, NB), 512, 0, stream>>>(row_start, s_cv, T2, BT);
  gemm_kernel<<<4 * NB + 1152, 256, 0, stream>>>(A, BT, row_start, s_cv, out);
}